// Round 12
// baseline (169.277 us; speedup 1.0000x reference)
//
#include <hip/hip_runtime.h>
#include <hip/hip_bf16.h>

// DilatedAttention: B=2, S=8192, D=1024, H=16, hd=64, SEGMENT=2048, DILATION=2
// -> n_seg=4, L=1024, tokens = 8192. Gathered x row for token t:
//   xrow = (t>>10)*2048 + (t&1023)*2
#define TOKENS  8192
// softmax scale folded into Q at QKV epilogue: 0.125 * log2(e)
#define QK_SC2  0.1803368801f

typedef short  short8 __attribute__((ext_vector_type(8)));
typedef float  f32x4  __attribute__((ext_vector_type(4)));
typedef float  f32x16 __attribute__((ext_vector_type(16)));
typedef unsigned short us4 __attribute__((ext_vector_type(4)));

__device__ __forceinline__ unsigned short f2bf_rne(float f) {
    unsigned u = __float_as_uint(f);
    unsigned r = (u + 0x7FFFu + ((u >> 16) & 1u)) >> 16;
    return (unsigned short)r;
}
// HW packed fp32->bf16 (RNE): D[15:0]=bf16(a), D[31:16]=bf16(b)
__device__ __forceinline__ unsigned cvt_pk_bf16(float a, float b) {
    unsigned r;
    asm("v_cvt_pk_bf16_f32 %0, %1, %2" : "=v"(r) : "v"(a), "v"(b));
    return r;
}
// v_permlane32_swap_b32: exchanges DATA0 lanes 32-63 with DATA1 lanes 0-31.
__device__ __forceinline__ void permlane32_swap(unsigned &a, unsigned &b) {
    asm("v_permlane32_swap_b32 %0, %1" : "+v"(a), "+v"(b));
}
__device__ __forceinline__ void gld16(const void* gptr, void* lptr) {
    __builtin_amdgcn_global_load_lds(
        (const __attribute__((address_space(1))) void*)gptr,
        (__attribute__((address_space(3))) void*)lptr, 16, 0, 0);
}

// ---------------------------------------------------------------------------
// prep_x: gather + fp32 -> bf16 (hi only).  Ax[t][k], stride 1024.
// ---------------------------------------------------------------------------
__global__ __launch_bounds__(256)
void prep_x_kernel(const float* __restrict__ x, unsigned short* __restrict__ Ax)
{
    const int t = blockIdx.x;
    const int c = threadIdx.x * 4;
    const long xrow = (long)((t >> 10) * 2048 + (t & 1023) * 2);
    float4 v = *reinterpret_cast<const float4*>(&x[xrow * 1024 + c]);
    us4 hv;
    hv[0] = f2bf_rne(v.x);
    hv[1] = f2bf_rne(v.y);
    hv[2] = f2bf_rne(v.z);
    hv[3] = f2bf_rne(v.w);
    *reinterpret_cast<us4*>(&Ax[(size_t)t * 1024 + c]) = hv;
}

// ---------------------------------------------------------------------------
// prep_w2: both weights in one launch.  W[1024][N] fp32 -> Wt[N][1024] bf16
// (transposed, hi only).  blockIdx.x < 96 -> Wqkv, else Wout.
// ---------------------------------------------------------------------------
__global__ __launch_bounds__(256)
void prep_w2_kernel(const float* __restrict__ Wq, const float* __restrict__ Wo,
                    unsigned short* __restrict__ Wqt, unsigned short* __restrict__ Wot)
{
    __shared__ float T[32][33];
    const int bx = blockIdx.x;
    const float* W;
    unsigned short* Wt;
    int N, n0;
    if (bx < 96) { W = Wq; Wt = Wqt; N = 3072; n0 = bx * 32; }
    else         { W = Wo; Wt = Wot; N = 1024; n0 = (bx - 96) * 32; }
    const int k0 = blockIdx.y * 32;
    const int tid = threadIdx.x;
#pragma unroll
    for (int p = 0; p < 4; p++) {
        int r = p * 8 + (tid >> 5), c = tid & 31;
        T[r][c] = W[(long)(k0 + r) * N + n0 + c];
    }
    __syncthreads();
#pragma unroll
    for (int p = 0; p < 4; p++) {
        int on = p * 8 + (tid >> 5), ok = tid & 31;
        Wt[(size_t)(n0 + on) * 1024 + k0 + ok] = f2bf_rne(T[ok][on]);
    }
}

// ---------------------------------------------------------------------------
// MFMA GEMM, phase-interleaved (structure at its measured ~850 TF ceiling).
//   BM=128, BN=256, BK=64, 512 threads (8 waves 2Mx4N), 64x64 out/wave.
//   3 LDS buffers x 48KB, prefetch distance 2, counted vmcnt(6).
// ASPLIT=1: A is [rows][2048] hi|lo, 2 K-segments, 32 tiles.
// ASPLIT=0: A is [rows][1024] hi only, 1 segment, 16 tiles (pure bf16).
// EPI=0: C fp32 = A*B + bias.
// EPI=1: QKV epilogue -> Q (pre-scaled by QK_SC2) / K bf16 head-major;
//        V direct-transposed to Vt.
// ---------------------------------------------------------------------------
template<int EPI, int ASPLIT>
__global__ __launch_bounds__(512, 1)
void gemm2p_kernel(const unsigned short* __restrict__ A,
                   const unsigned short* __restrict__ Bt,
                   const float* __restrict__ bias,
                   float* __restrict__ C,
                   unsigned short* __restrict__ Qb,
                   unsigned short* __restrict__ Kb,
                   unsigned short* __restrict__ Vt,
                   int N, int NBX)
{
    __shared__ __align__(16) char lds[3 * 49152];   // 144 KB

    const int NT = ASPLIT ? 32 : 16;
    const int ASTRIDE = ASPLIT ? 2048 : 1024;

    const int tid = threadIdx.x;
    const int l = tid & 63, w = tid >> 6;
    const int wm = w >> 2, wn = w & 3;       // 2M x 4N waves
    const int l15 = l & 15;

    // XCD-aware bijective swizzle (gridDim.x % 8 == 0 by construction)
    const int cpx = gridDim.x >> 3;
    const int wg = (blockIdx.x & 7) * cpx + (blockIdx.x >> 3);
    const int by = wg / NBX, bx = wg - by * NBX;
    const int trow0 = by * 128, col0 = bx * 256;

    // ---- staging maps: 6 slots/tile, issue order = (A,A,Bh0,Bh0),(Bh1,Bh1)
    size_t gOff[6];
    int    lOff[6];
    {
        const int c = tid & 7;
#pragma unroll
        for (int p = 0; p < 2; p++) {
            {   // A slots 0,1: rows 0..127 plain
                const int row = (tid + p * 512) >> 3;
                const int cg = c ^ (row & 7);
                gOff[p] = (size_t)(trow0 + row) * ASTRIDE + cg * 8;
                lOff[p] = row * 128 + c * 16;
            }
            {   // B half0 slots 2,3: rows {0-31,64-95,128-159,192-223}
                const int u = (tid + p * 512) >> 3;
                const int row = ((u >> 5) << 6) + (u & 31);
                const int cg = c ^ (row & 7);
                gOff[2 + p] = (size_t)(col0 + row) * 1024 + cg * 8;
                lOff[2 + p] = 16384 + row * 128 + c * 16;
            }
            {   // B half1 slots 4,5: rows {32-63,96-127,160-191,224-255}
                const int u = (tid + p * 512) >> 3;
                const int row = ((u >> 5) << 6) + 32 + (u & 31);
                const int cg = c ^ (row & 7);
                gOff[4 + p] = (size_t)(col0 + row) * 1024 + cg * 8;
                lOff[4 + p] = 16384 + row * 128 + c * 16;
            }
        }
    }

    // fragment-read lane constants (swizzled in-row byte offsets, k-halves)
    const int offs0 = (((l >> 4) * 16)     ) ^ ((l & 7) << 4);
    const int offs1 = (((l >> 4) * 16) + 64) ^ ((l & 7) << 4);

    f32x4 acc[4][4];
#pragma unroll
    for (int i = 0; i < 4; i++)
#pragma unroll
        for (int j = 0; j < 4; j++) acc[i][j] = (f32x4){0.f, 0.f, 0.f, 0.f};

    // ---- prologue: stage K-tiles 0,1 (6 gld16 each) ----
#pragma unroll
    for (int t0 = 0; t0 < 2; ++t0) {
        char* buf = lds + t0 * 49152;
        const int ac = t0 * 64;              // seg 0 -> A-hi, B-hi
        gld16(&A [gOff[0] + ac], buf + lOff[0]);
        gld16(&A [gOff[1] + ac], buf + lOff[1]);
        gld16(&Bt[gOff[2] + ac], buf + lOff[2]);
        gld16(&Bt[gOff[3] + ac], buf + lOff[3]);
        gld16(&Bt[gOff[4] + ac], buf + lOff[4]);
        gld16(&Bt[gOff[5] + ac], buf + lOff[5]);
    }
    asm volatile("s_waitcnt vmcnt(6)" ::: "memory");   // tile 0 landed
    __builtin_amdgcn_s_barrier();

    int bc3 = 0;
    for (int t = 0; t < NT; ++t) {
        char* buf = lds + bc3 * 49152;
        const int bn = (bc3 >= 1) ? bc3 - 1 : 2;       // (bc3+2)%3
        char* nbuf = lds + bn * 49152;
        const int tp = t + 2;
        const bool pf = (tp < NT);
        const int ac  = pf ? (ASPLIT ? (((tp >> 4) ? 1024 : 0) + (tp & 15) * 64)
                                     : tp * 64) : 0;
        const int bcc = pf ? ((tp & 15) * 64) : 0;

        // ===================== phase 0 =====================
        short8 af[4][2], bf0[2][2], bf1[2][2];
#pragma unroll
        for (int i = 0; i < 4; ++i) {
            const int r = wm * 64 + i * 16 + l15;
            af[i][0] = *reinterpret_cast<const short8*>(buf + r * 128 + offs0);
            af[i][1] = *reinterpret_cast<const short8*>(buf + r * 128 + offs1);
        }
#pragma unroll
        for (int j = 0; j < 2; ++j) {
            const int r = wn * 64 + j * 16 + l15;
            bf0[j][0] = *reinterpret_cast<const short8*>(buf + 16384 + r * 128 + offs0);
            bf0[j][1] = *reinterpret_cast<const short8*>(buf + 16384 + r * 128 + offs1);
        }
        if (pf) {
            gld16(&A [gOff[0] + ac],  nbuf + lOff[0]);
            gld16(&A [gOff[1] + ac],  nbuf + lOff[1]);
            gld16(&Bt[gOff[2] + bcc], nbuf + lOff[2]);
            gld16(&Bt[gOff[3] + bcc], nbuf + lOff[3]);
        }
        __builtin_amdgcn_s_barrier();
        __builtin_amdgcn_s_setprio(1);
#pragma unroll
        for (int i = 0; i < 4; ++i)
#pragma unroll
            for (int j = 0; j < 2; ++j) {
                acc[i][j] = __builtin_amdgcn_mfma_f32_16x16x32_bf16(
                    af[i][0], bf0[j][0], acc[i][j], 0, 0, 0);
                acc[i][j] = __builtin_amdgcn_mfma_f32_16x16x32_bf16(
                    af[i][1], bf0[j][1], acc[i][j], 0, 0, 0);
            }
        __builtin_amdgcn_s_setprio(0);
        __builtin_amdgcn_s_barrier();

        // ===================== phase 1 =====================
#pragma unroll
        for (int j = 0; j < 2; ++j) {
            const int r = wn * 64 + 32 + j * 16 + l15;
            bf1[j][0] = *reinterpret_cast<const short8*>(buf + 16384 + r * 128 + offs0);
            bf1[j][1] = *reinterpret_cast<const short8*>(buf + 16384 + r * 128 + offs1);
        }
        if (pf) {
            gld16(&Bt[gOff[4] + bcc], nbuf + lOff[4]);
            gld16(&Bt[gOff[5] + bcc], nbuf + lOff[5]);
        }
        __builtin_amdgcn_s_barrier();
        __builtin_amdgcn_s_setprio(1);
#pragma unroll
        for (int i = 0; i < 4; ++i)
#pragma unroll
            for (int j = 0; j < 2; ++j) {
                acc[i][2 + j] = __builtin_amdgcn_mfma_f32_16x16x32_bf16(
                    af[i][0], bf1[j][0], acc[i][2 + j], 0, 0, 0);
                acc[i][2 + j] = __builtin_amdgcn_mfma_f32_16x16x32_bf16(
                    af[i][1], bf1[j][1], acc[i][2 + j], 0, 0, 0);
            }
        __builtin_amdgcn_s_setprio(0);

        // ---- tile boundary: counted vmcnt; tail drains fully
        if (pf) asm volatile("s_waitcnt vmcnt(6)" ::: "memory");
        else    asm volatile("s_waitcnt vmcnt(0)" ::: "memory");
        __builtin_amdgcn_s_barrier();

        bc3 = (bc3 >= 2) ? 0 : bc3 + 1;
    }

    // ---- epilogue ----
    // C/D layout (verified m89/m91): col = lane&15, row = (lane>>4)*4 + reg
#pragma unroll
    for (int j = 0; j < 4; ++j) {
        const int gc = col0 + wn * 64 + j * 16 + l15;
        const float bv = bias[gc];
        if (EPI == 0) {
#pragma unroll
            for (int i = 0; i < 4; ++i) {
                const int gr0 = trow0 + wm * 64 + i * 16 + (l >> 4) * 4;
#pragma unroll
                for (int r = 0; r < 4; ++r)
                    C[(size_t)(gr0 + r) * N + gc] = acc[i][j][r] + bv;
            }
        } else {
            const int which = gc >> 10;
            const int head  = (gc >> 6) & 15;
            const int d     = gc & 63;
            if (which == 2) {
                // V: direct-transposed write Vt[bsh][d][l], 4 tokens / us4
#pragma unroll
                for (int i = 0; i < 4; ++i) {
                    const int gr0 = trow0 + wm * 64 + i * 16 + (l >> 4) * 4;
                    const size_t base =
                        ((size_t)((gr0 >> 10) * 16 + head) << 16)
                        + (size_t)d * 1024 + (gr0 & 1023);
                    union { unsigned u[2]; us4 v; } pk;
                    pk.u[0] = cvt_pk_bf16(acc[i][j][0] + bv, acc[i][j][1] + bv);
                    pk.u[1] = cvt_pk_bf16(acc[i][j][2] + bv, acc[i][j][3] + bv);
                    *reinterpret_cast<us4*>(&Vt[base]) = pk.v;
                }
            } else {
                // Q gets the softmax scale folded in (exp2-domain)
                unsigned short* dst = (which == 0) ? Qb : Kb;
                const float sc = (which == 0) ? QK_SC2 : 1.f;
#pragma unroll
                for (int i = 0; i < 4; ++i) {
                    const int gr0 = trow0 + wm * 64 + i * 16 + (l >> 4) * 4;
                    const unsigned a01 = cvt_pk_bf16((acc[i][j][0] + bv) * sc,
                                                     (acc[i][j][1] + bv) * sc);
                    const unsigned a23 = cvt_pk_bf16((acc[i][j][2] + bv) * sc,
                                                     (acc[i][j][3] + bv) * sc);
                    const size_t adr0 = ((size_t)((gr0 >> 10) * 16 + head) << 16)
                                      + (size_t)(gr0 & 1023) * 64 + d;
                    dst[adr0]           = (unsigned short)a01;
                    dst[adr0 + 64]      = (unsigned short)(a01 >> 16);
                    dst[adr0 + 128]     = (unsigned short)a23;
                    dst[adr0 + 192]     = (unsigned short)(a23 >> 16);
                }
            }
        }
    }
}

// ---------------------------------------------------------------------------
// MFMA flash attention, 32x32x16, swapped QK^T, q64-per-wave:
// each wave owns 64 q-rows (2 q-halves); K and V fragments are read from
// LDS ONCE per tile into registers and reused for both q-halves
// (0.5 ds_read_b128 per MFMA; K/V global re-reads halved: 4 q-chunks/head).
// Double-buffered staging; static-max exp2 softmax; permlane P-redistribute.
// Block = 4 waves x 64 q = 256 q; grid = 128 bsh x 4 qc = 512 (2 blocks/CU).
// Writes ctx bf16 (hi only) [token][1024].
// ---------------------------------------------------------------------------
__global__ __launch_bounds__(256)
void attn_mfma_kernel(const unsigned short* __restrict__ Qb,
                      const unsigned short* __restrict__ Kb,
                      const unsigned short* __restrict__ Vt,
                      unsigned short* __restrict__ ctx)
{
    __shared__ __align__(16) char Ks[2][8192];   // K[key][d] tiles, swizzled
    __shared__ __align__(16) char Vs[2][8192];   // V^T[d][key] tiles, swizzled

    const int id  = blockIdx.x;               // 512 blocks; id%8 == bsh&7
    const int bsh = (id >> 5) * 8 + (id & 7); // 0..127
    const int qc  = (id >> 3) & 3;            // 0..3
    const int bseg = bsh >> 4, h = bsh & 15;
    const int tid = threadIdx.x;
    const int w = tid >> 6, l = tid & 63;
    const int H = l >> 5, lq = l & 31;
    const int q0 = qc * 256 + w * 64;

    const size_t hbytes = (size_t)bsh << 17;  // bsh * 65536 elems * 2B

    // staging lane constants (2 chunks of K + 2 of V per thread)
    int srowA[2], scolA[2], sdst[2];
#pragma unroll
    for (int p = 0; p < 2; p++) {
        const int c = w + p * 4;                 // chunk 0..7
        const int o = c * 1024 + l * 16;         // byte offset in tile
        srowA[p] = o >> 7;                       // key (K) / d (V^T)
        scolA[p] = (o & 127) ^ ((l >> 3) << 4);  // pre-swizzled src byte
        sdst[p]  = c * 1024;
    }

    // Q B-fragments for both q-halves (pre-scaled by 0.125*log2e)
    short8 qf[2][4];
#pragma unroll
    for (int qs = 0; qs < 2; qs++) {
        const char* qsrc = (const char*)Qb + hbytes
                         + (size_t)(q0 + qs * 32 + lq) * 128;
#pragma unroll
        for (int ks = 0; ks < 4; ks++)
            qf[qs][ks] = *reinterpret_cast<const short8*>(qsrc + ks * 32 + H * 16);
    }

    f32x16 acc[2][2];
#pragma unroll
    for (int qs = 0; qs < 2; qs++)
#pragma unroll
        for (int vh = 0; vh < 2; vh++)
#pragma unroll
            for (int r = 0; r < 16; r++) acc[qs][vh][r] = 0.f;
    float lsum0 = 0.f, lsum1 = 0.f;

    // ---- prologue: stage tile 0 into buf 0 ----
#pragma unroll
    for (int p = 0; p < 2; p++) {
        gld16((const char*)Kb + hbytes + (size_t)(srowA[p]) * 128 + scolA[p],
              Ks[0] + sdst[p]);
        gld16((const char*)Vt + hbytes + (size_t)srowA[p] * 2048 + scolA[p],
              Vs[0] + sdst[p]);
    }
    __syncthreads();

    for (int t = 0; t < 16; t++) {
        const int cur = t & 1;

        // ---- stage tile t+1 into the other buffer (hidden under compute)
        if (t + 1 < 16) {
            const int nb = cur ^ 1;
#pragma unroll
            for (int p = 0; p < 2; p++) {
                gld16((const char*)Kb + hbytes
                          + (size_t)((t + 1) * 64 + srowA[p]) * 128 + scolA[p],
                      Ks[nb] + sdst[p]);
                gld16((const char*)Vt + hbytes
                          + (size_t)srowA[p] * 2048 + (t + 1) * 128 + scolA[p],
                      Vs[nb] + sdst[p]);
            }
        }

        // ---- read K fragments ONCE (8 b128), reused by both q-halves ----
        short8 kfr[4][2];
#pragma unroll
        for (int ks = 0; ks < 4; ks++) {
            const int b0 = (lq * 128 + ks * 32 + H * 16) ^ ((lq & 7) << 4);
            kfr[ks][0] = *reinterpret_cast<const short8*>(Ks[cur] + b0);
            kfr[ks][1] = *reinterpret_cast<const short8*>(Ks[cur] + b0 + 4096);
        }
        // ---- read V fragments ONCE (8 b128), reused by both q-halves ----
        short8 vfr[2][2][2];
#pragma unroll
        for (int kf = 0; kf < 2; kf++)
#pragma unroll
            for (int tt = 0; tt < 2; tt++) {
                const int vb0 = (lq * 128 + kf * 64 + tt * 32 + H * 16)
                              ^ ((lq & 7) << 4);
                vfr[kf][tt][0] = *reinterpret_cast<const short8*>(Vs[cur] + vb0);
                vfr[kf][tt][1] = *reinterpret_cast<const short8*>(Vs[cur] + vb0 + 4096);
            }

#pragma unroll
        for (int qs = 0; qs < 2; qs++) {
            // ---- S^T = mfma(K, Q): exp2-domain scores ----
            f32x16 s0, s1;
#pragma unroll
            for (int r = 0; r < 16; r++) { s0[r] = 0.f; s1[r] = 0.f; }
#pragma unroll
            for (int ks = 0; ks < 4; ks++) {
                s0 = __builtin_amdgcn_mfma_f32_32x32x16_bf16(
                    kfr[ks][0], qf[qs][ks], s0, 0, 0, 0);
                s1 = __builtin_amdgcn_mfma_f32_32x32x16_bf16(
                    kfr[ks][1], qf[qs][ks], s1, 0, 0, 0);
            }

            // ---- static-max softmax: p = exp2(s) directly ----
            float pv[32];
            float ps = 0.f;
#pragma unroll
            for (int r = 0; r < 16; r++) {
                pv[r]      = __builtin_amdgcn_exp2f(s0[r]);
                pv[16 + r] = __builtin_amdgcn_exp2f(s1[r]);
            }
#pragma unroll
            for (int r = 0; r < 32; r++) ps += pv[r];
            if (qs == 0) lsum0 += ps; else lsum1 += ps;

            // ---- P redistribution via permlane32_swap + PV MFMAs ----
#pragma unroll
            for (int kf = 0; kf < 2; kf++) {
                unsigned c8[8];
#pragma unroll
                for (int i = 0; i < 8; i++)
                    c8[i] = cvt_pk_bf16(pv[kf * 16 + 2 * i],
                                        pv[kf * 16 + 2 * i + 1]);
#pragma unroll
                for (int tt = 0; tt < 2; tt++) {
                    const int b = tt * 4;
                    unsigned u0 = c8[b + 0], u2 = c8[b + 2];
                    unsigned u1 = c8[b + 1], u3 = c8[b + 3];
                    permlane32_swap(u0, u2);
                    permlane32_swap(u1, u3);
                    union { unsigned u[4]; short8 v; } pa;
                    pa.u[0] = u0; pa.u[1] = u1; pa.u[2] = u2; pa.u[3] = u3;
                    acc[qs][0] = __builtin_amdgcn_mfma_f32_32x32x16_bf16(
                        pa.v, vfr[kf][tt][0], acc[qs][0], 0, 0, 0);
                    acc[qs][1] = __builtin_amdgcn_mfma_f32_32x32x16_bf16(
                        pa.v, vfr[kf][tt][1], acc[qs][1], 0, 0, 0);
                }
            }
        }

        // one sync per tile: drains the t+1 staging (issued a full compute
        // phase ago -> hidden) and protects buffer reuse
        if (t + 1 < 16) __syncthreads();
    }

    // ---- epilogue: normalize, pack, store (ctx bf16 hi-only) ----
#pragma unroll
    for (int qs = 0; qs < 2; qs++) {
        const float ls = (qs == 0) ? lsum0 : lsum1;
        const float lt = ls + __shfl_xor(ls, 32);
#pragma unroll
        for (int r = 0; r < 16; r++) {
            const int qrow = (r & 3) + 8 * (r >> 2) + 4 * H;
            const float inv = 1.f / __shfl(lt, qrow);
            const size_t tok = (size_t)bseg * 1024 + q0 + qs * 32 + qrow;
            unsigned short* p0 = ctx + tok * 1024 + h * 64 + lq;
            const unsigned pk = cvt_pk_bf16(acc[qs][0][r] * inv,
                                            acc[qs][1][r] * inv);
            p0[0]  = (unsigned short)pk;
            p0[32] = (unsigned short)(pk >> 16);
        }
    }
}

// ---------------------------------------------------------------------------
extern "C" void kernel_launch(void* const* d_in, const int* in_sizes, int n_in,
                              void* d_out, int out_size, void* d_ws, size_t ws_size,
                              hipStream_t stream)
{
    const float* x    = (const float*)d_in[0];
    const float* Wqkv = (const float*)d_in[1];
    const float* bqkv = (const float*)d_in[2];
    const float* Wout = (const float*)d_in[3];
    const float* bout = (const float*)d_in[4];
    float* out = (float*)d_out;

    // workspace layout
    char* ws = (char*)d_ws;
    unsigned short* Ax  = (unsigned short*)(ws);                    // 16 MB (hi only)
    unsigned short* Wqt = (unsigned short*)(ws + 33554432);         //  6 MB (hi only)
    unsigned short* Wot = (unsigned short*)(ws + 46137344);         //  2 MB (hi only)
    unsigned short* Qb  = (unsigned short*)(ws + 50331648);         // 16 MB
    unsigned short* Kb  = (unsigned short*)(ws + 67108864);         // 16 MB
    unsigned short* Vt  = (unsigned short*)(ws + 100663296);        // 16 MB
    unsigned short* ctx = (unsigned short*)(ws + 117440512);        // 16 MB (hi only)

    prep_x_kernel<<<TOKENS, 256, 0, stream>>>(x, Ax);
    prep_w2_kernel<<<dim3(128, 32), 256, 0, stream>>>(Wqkv, Wout, Wqt, Wot);

    // QKV projection (pure bf16, K=1024, 16 tiles) -> Q(scaled)/K + Vt.
    // grid = (8192/128)*(3072/256) = 64*12 = 768 blocks = 3 exact rounds.
    gemm2p_kernel<1, 0><<<768, 512, 0, stream>>>(
        Ax, Wqt, bqkv, (float*)nullptr, Qb, Kb, Vt, 3072, 12);

    // q64 attention: 512 blocks (2/CU)
    attn_mfma_kernel<<<512, 256, 0, stream>>>(Qb, Kb, Vt, ctx);

    // output projection (pure bf16 ctx, 16 tiles) -> fp32 out.
    // grid = 64*4 = 256 blocks = 1 round.
    gemm2p_kernel<0, 0><<<256, 512, 0, stream>>>(
        ctx, Wot, bout, out, (unsigned short*)nullptr,
        (unsigned short*)nullptr, (unsigned short*)nullptr, 1024, 4);
}

// Round 13
// 153.765 us; speedup vs baseline: 1.1009x; 1.1009x over previous
//
#include <hip/hip_runtime.h>
#include <hip/hip_bf16.h>

// DilatedAttention: B=2, S=8192, D=1024, H=16, hd=64, SEGMENT=2048, DILATION=2
// -> n_seg=4, L=1024, tokens = 8192. Gathered x row for token t:
//   xrow = (t>>10)*2048 + (t&1023)*2
#define TOKENS  8192
// softmax scale folded into Q at QKV epilogue: 0.125 * log2(e)
#define QK_SC2  0.1803368801f

typedef short  short8 __attribute__((ext_vector_type(8)));
typedef float  f32x4  __attribute__((ext_vector_type(4)));
typedef float  f32x16 __attribute__((ext_vector_type(16)));
typedef unsigned short us4 __attribute__((ext_vector_type(4)));

__device__ __forceinline__ unsigned short f2bf_rne(float f) {
    unsigned u = __float_as_uint(f);
    unsigned r = (u + 0x7FFFu + ((u >> 16) & 1u)) >> 16;
    return (unsigned short)r;
}
// HW packed fp32->bf16 (RNE): D[15:0]=bf16(a), D[31:16]=bf16(b)
__device__ __forceinline__ unsigned cvt_pk_bf16(float a, float b) {
    unsigned r;
    asm("v_cvt_pk_bf16_f32 %0, %1, %2" : "=v"(r) : "v"(a), "v"(b));
    return r;
}
// v_permlane32_swap_b32: exchanges DATA0 lanes 32-63 with DATA1 lanes 0-31.
__device__ __forceinline__ void permlane32_swap(unsigned &a, unsigned &b) {
    asm("v_permlane32_swap_b32 %0, %1" : "+v"(a), "+v"(b));
}
__device__ __forceinline__ void gld16(const void* gptr, void* lptr) {
    __builtin_amdgcn_global_load_lds(
        (const __attribute__((address_space(1))) void*)gptr,
        (__attribute__((address_space(3))) void*)lptr, 16, 0, 0);
}

// ---------------------------------------------------------------------------
// prep_all: one launch for all input prep.
//   blocks [0, 8192):        x gather + fp32->bf16 (hi) -> Ax[t][1024]
//   blocks [8192, 8192+4096): W transpose fp32->bf16 (hi):
//       idx = bid - 8192; bx = idx & 127 (<96 -> Wqkv, else Wout); by = idx>>7
// ---------------------------------------------------------------------------
__global__ __launch_bounds__(256)
void prep_all_kernel(const float* __restrict__ x,
                     const float* __restrict__ Wq, const float* __restrict__ Wo,
                     unsigned short* __restrict__ Ax,
                     unsigned short* __restrict__ Wqt,
                     unsigned short* __restrict__ Wot)
{
    const int bid = blockIdx.x;
    const int tid = threadIdx.x;
    if (bid < 8192) {
        const int t = bid;
        const int c = tid * 4;
        const long xrow = (long)((t >> 10) * 2048 + (t & 1023) * 2);
        float4 v = *reinterpret_cast<const float4*>(&x[xrow * 1024 + c]);
        us4 hv;
        hv[0] = f2bf_rne(v.x);
        hv[1] = f2bf_rne(v.y);
        hv[2] = f2bf_rne(v.z);
        hv[3] = f2bf_rne(v.w);
        *reinterpret_cast<us4*>(&Ax[(size_t)t * 1024 + c]) = hv;
        return;
    }
    __shared__ float T[32][33];
    const int idx = bid - 8192;
    const int bx = idx & 127, by = idx >> 7;
    const float* W;
    unsigned short* Wt;
    int N, n0;
    if (bx < 96) { W = Wq; Wt = Wqt; N = 3072; n0 = bx * 32; }
    else         { W = Wo; Wt = Wot; N = 1024; n0 = (bx - 96) * 32; }
    const int k0 = by * 32;
#pragma unroll
    for (int p = 0; p < 4; p++) {
        int r = p * 8 + (tid >> 5), c = tid & 31;
        T[r][c] = W[(long)(k0 + r) * N + n0 + c];
    }
    __syncthreads();
#pragma unroll
    for (int p = 0; p < 4; p++) {
        int on = p * 8 + (tid >> 5), ok = tid & 31;
        Wt[(size_t)(n0 + on) * 1024 + k0 + ok] = f2bf_rne(T[ok][on]);
    }
}

// ---------------------------------------------------------------------------
// MFMA GEMM, phase-interleaved (structure at its measured ~850 TF ceiling).
//   BM=128, BN=256, BK=64, 512 threads (8 waves 2Mx4N), 64x64 out/wave.
//   3 LDS buffers x 48KB, prefetch distance 2, counted vmcnt(6).
// ASPLIT=1: A is [rows][2048] hi|lo, 2 K-segments, 32 tiles.
// ASPLIT=0: A is [rows][1024] hi only, 1 segment, 16 tiles (pure bf16).
// EPI=0: C fp32 = A*B + bias.
// EPI=1: QKV epilogue -> Q (pre-scaled by QK_SC2) / K bf16 head-major;
//        V direct-transposed to Vt.
// ---------------------------------------------------------------------------
template<int EPI, int ASPLIT>
__global__ __launch_bounds__(512, 1)
void gemm2p_kernel(const unsigned short* __restrict__ A,
                   const unsigned short* __restrict__ Bt,
                   const float* __restrict__ bias,
                   float* __restrict__ C,
                   unsigned short* __restrict__ Qb,
                   unsigned short* __restrict__ Kb,
                   unsigned short* __restrict__ Vt,
                   int N, int NBX)
{
    __shared__ __align__(16) char lds[3 * 49152];   // 144 KB

    const int NT = ASPLIT ? 32 : 16;
    const int ASTRIDE = ASPLIT ? 2048 : 1024;

    const int tid = threadIdx.x;
    const int l = tid & 63, w = tid >> 6;
    const int wm = w >> 2, wn = w & 3;       // 2M x 4N waves
    const int l15 = l & 15;

    // XCD-aware bijective swizzle (gridDim.x % 8 == 0 by construction)
    const int cpx = gridDim.x >> 3;
    const int wg = (blockIdx.x & 7) * cpx + (blockIdx.x >> 3);
    const int by = wg / NBX, bx = wg - by * NBX;
    const int trow0 = by * 128, col0 = bx * 256;

    // ---- staging maps: 6 slots/tile, issue order = (A,A,Bh0,Bh0),(Bh1,Bh1)
    size_t gOff[6];
    int    lOff[6];
    {
        const int c = tid & 7;
#pragma unroll
        for (int p = 0; p < 2; p++) {
            {   // A slots 0,1: rows 0..127 plain
                const int row = (tid + p * 512) >> 3;
                const int cg = c ^ (row & 7);
                gOff[p] = (size_t)(trow0 + row) * ASTRIDE + cg * 8;
                lOff[p] = row * 128 + c * 16;
            }
            {   // B half0 slots 2,3: rows {0-31,64-95,128-159,192-223}
                const int u = (tid + p * 512) >> 3;
                const int row = ((u >> 5) << 6) + (u & 31);
                const int cg = c ^ (row & 7);
                gOff[2 + p] = (size_t)(col0 + row) * 1024 + cg * 8;
                lOff[2 + p] = 16384 + row * 128 + c * 16;
            }
            {   // B half1 slots 4,5: rows {32-63,96-127,160-191,224-255}
                const int u = (tid + p * 512) >> 3;
                const int row = ((u >> 5) << 6) + 32 + (u & 31);
                const int cg = c ^ (row & 7);
                gOff[4 + p] = (size_t)(col0 + row) * 1024 + cg * 8;
                lOff[4 + p] = 16384 + row * 128 + c * 16;
            }
        }
    }

    // fragment-read lane constants (swizzled in-row byte offsets, k-halves)
    const int offs0 = (((l >> 4) * 16)     ) ^ ((l & 7) << 4);
    const int offs1 = (((l >> 4) * 16) + 64) ^ ((l & 7) << 4);

    f32x4 acc[4][4];
#pragma unroll
    for (int i = 0; i < 4; i++)
#pragma unroll
        for (int j = 0; j < 4; j++) acc[i][j] = (f32x4){0.f, 0.f, 0.f, 0.f};

    // ---- prologue: stage K-tiles 0,1 (6 gld16 each) ----
#pragma unroll
    for (int t0 = 0; t0 < 2; ++t0) {
        char* buf = lds + t0 * 49152;
        const int ac = t0 * 64;              // seg 0 -> A-hi, B-hi
        gld16(&A [gOff[0] + ac], buf + lOff[0]);
        gld16(&A [gOff[1] + ac], buf + lOff[1]);
        gld16(&Bt[gOff[2] + ac], buf + lOff[2]);
        gld16(&Bt[gOff[3] + ac], buf + lOff[3]);
        gld16(&Bt[gOff[4] + ac], buf + lOff[4]);
        gld16(&Bt[gOff[5] + ac], buf + lOff[5]);
    }
    asm volatile("s_waitcnt vmcnt(6)" ::: "memory");   // tile 0 landed
    __builtin_amdgcn_s_barrier();

    int bc3 = 0;
    for (int t = 0; t < NT; ++t) {
        char* buf = lds + bc3 * 49152;
        const int bn = (bc3 >= 1) ? bc3 - 1 : 2;       // (bc3+2)%3
        char* nbuf = lds + bn * 49152;
        const int tp = t + 2;
        const bool pf = (tp < NT);
        const int ac  = pf ? (ASPLIT ? (((tp >> 4) ? 1024 : 0) + (tp & 15) * 64)
                                     : tp * 64) : 0;
        const int bcc = pf ? ((tp & 15) * 64) : 0;

        // ===================== phase 0 =====================
        short8 af[4][2], bf0[2][2], bf1[2][2];
#pragma unroll
        for (int i = 0; i < 4; ++i) {
            const int r = wm * 64 + i * 16 + l15;
            af[i][0] = *reinterpret_cast<const short8*>(buf + r * 128 + offs0);
            af[i][1] = *reinterpret_cast<const short8*>(buf + r * 128 + offs1);
        }
#pragma unroll
        for (int j = 0; j < 2; ++j) {
            const int r = wn * 64 + j * 16 + l15;
            bf0[j][0] = *reinterpret_cast<const short8*>(buf + 16384 + r * 128 + offs0);
            bf0[j][1] = *reinterpret_cast<const short8*>(buf + 16384 + r * 128 + offs1);
        }
        if (pf) {
            gld16(&A [gOff[0] + ac],  nbuf + lOff[0]);
            gld16(&A [gOff[1] + ac],  nbuf + lOff[1]);
            gld16(&Bt[gOff[2] + bcc], nbuf + lOff[2]);
            gld16(&Bt[gOff[3] + bcc], nbuf + lOff[3]);
        }
        __builtin_amdgcn_s_barrier();
        __builtin_amdgcn_s_setprio(1);
#pragma unroll
        for (int i = 0; i < 4; ++i)
#pragma unroll
            for (int j = 0; j < 2; ++j) {
                acc[i][j] = __builtin_amdgcn_mfma_f32_16x16x32_bf16(
                    af[i][0], bf0[j][0], acc[i][j], 0, 0, 0);
                acc[i][j] = __builtin_amdgcn_mfma_f32_16x16x32_bf16(
                    af[i][1], bf0[j][1], acc[i][j], 0, 0, 0);
            }
        __builtin_amdgcn_s_setprio(0);
        __builtin_amdgcn_s_barrier();

        // ===================== phase 1 =====================
#pragma unroll
        for (int j = 0; j < 2; ++j) {
            const int r = wn * 64 + 32 + j * 16 + l15;
            bf1[j][0] = *reinterpret_cast<const short8*>(buf + 16384 + r * 128 + offs0);
            bf1[j][1] = *reinterpret_cast<const short8*>(buf + 16384 + r * 128 + offs1);
        }
        if (pf) {
            gld16(&Bt[gOff[4] + bcc], nbuf + lOff[4]);
            gld16(&Bt[gOff[5] + bcc], nbuf + lOff[5]);
        }
        __builtin_amdgcn_s_barrier();
        __builtin_amdgcn_s_setprio(1);
#pragma unroll
        for (int i = 0; i < 4; ++i)
#pragma unroll
            for (int j = 0; j < 2; ++j) {
                acc[i][2 + j] = __builtin_amdgcn_mfma_f32_16x16x32_bf16(
                    af[i][0], bf1[j][0], acc[i][2 + j], 0, 0, 0);
                acc[i][2 + j] = __builtin_amdgcn_mfma_f32_16x16x32_bf16(
                    af[i][1], bf1[j][1], acc[i][2 + j], 0, 0, 0);
            }
        __builtin_amdgcn_s_setprio(0);

        // ---- tile boundary: counted vmcnt; tail drains fully
        if (pf) asm volatile("s_waitcnt vmcnt(6)" ::: "memory");
        else    asm volatile("s_waitcnt vmcnt(0)" ::: "memory");
        __builtin_amdgcn_s_barrier();

        bc3 = (bc3 >= 2) ? 0 : bc3 + 1;
    }

    // ---- epilogue ----
    // C/D layout (verified m89/m91): col = lane&15, row = (lane>>4)*4 + reg
#pragma unroll
    for (int j = 0; j < 4; ++j) {
        const int gc = col0 + wn * 64 + j * 16 + l15;
        const float bv = bias[gc];
        if (EPI == 0) {
#pragma unroll
            for (int i = 0; i < 4; ++i) {
                const int gr0 = trow0 + wm * 64 + i * 16 + (l >> 4) * 4;
#pragma unroll
                for (int r = 0; r < 4; ++r)
                    C[(size_t)(gr0 + r) * N + gc] = acc[i][j][r] + bv;
            }
        } else {
            const int which = gc >> 10;
            const int head  = (gc >> 6) & 15;
            const int d     = gc & 63;
            if (which == 2) {
                // V: direct-transposed write Vt[bsh][d][l], 4 tokens / us4
#pragma unroll
                for (int i = 0; i < 4; ++i) {
                    const int gr0 = trow0 + wm * 64 + i * 16 + (l >> 4) * 4;
                    const size_t base =
                        ((size_t)((gr0 >> 10) * 16 + head) << 16)
                        + (size_t)d * 1024 + (gr0 & 1023);
                    union { unsigned u[2]; us4 v; } pk;
                    pk.u[0] = cvt_pk_bf16(acc[i][j][0] + bv, acc[i][j][1] + bv);
                    pk.u[1] = cvt_pk_bf16(acc[i][j][2] + bv, acc[i][j][3] + bv);
                    *reinterpret_cast<us4*>(&Vt[base]) = pk.v;
                }
            } else {
                // Q gets the softmax scale folded in (exp2-domain)
                unsigned short* dst = (which == 0) ? Qb : Kb;
                const float sc = (which == 0) ? QK_SC2 : 1.f;
#pragma unroll
                for (int i = 0; i < 4; ++i) {
                    const int gr0 = trow0 + wm * 64 + i * 16 + (l >> 4) * 4;
                    const unsigned a01 = cvt_pk_bf16((acc[i][j][0] + bv) * sc,
                                                     (acc[i][j][1] + bv) * sc);
                    const unsigned a23 = cvt_pk_bf16((acc[i][j][2] + bv) * sc,
                                                     (acc[i][j][3] + bv) * sc);
                    const size_t adr0 = ((size_t)((gr0 >> 10) * 16 + head) << 16)
                                      + (size_t)(gr0 & 1023) * 64 + d;
                    dst[adr0]           = (unsigned short)a01;
                    dst[adr0 + 64]      = (unsigned short)(a01 >> 16);
                    dst[adr0 + 128]     = (unsigned short)a23;
                    dst[adr0 + 192]     = (unsigned short)(a23 >> 16);
                }
            }
        }
    }
}

// ---------------------------------------------------------------------------
// MFMA flash attention, 32x32x16, swapped QK^T (R11 configuration — the
// measured-best operating point: q32/wave, grid 1024, 4 blocks/CU).
// Double-buffered K/V staging; static-max exp2 softmax (base shift cancels
// in normalization; scores are O(5) so exp2 is fp32-safe);
// permlane32_swap P-redistribution.  Writes ctx bf16 (hi) [token][1024].
// ---------------------------------------------------------------------------
__global__ __launch_bounds__(256)
void attn_mfma_kernel(const unsigned short* __restrict__ Qb,
                      const unsigned short* __restrict__ Kb,
                      const unsigned short* __restrict__ Vt,
                      unsigned short* __restrict__ ctx)
{
    __shared__ __align__(16) char Ks[2][8192];   // K[key][d] tiles, swizzled
    __shared__ __align__(16) char Vs[2][8192];   // V^T[d][key] tiles, swizzled

    const int id  = blockIdx.x;               // id%8 == bsh&7 (XCD affinity)
    const int bsh = (id >> 6) * 8 + (id & 7); // 0..127
    const int qc  = (id >> 3) & 7;            // 0..7
    const int bseg = bsh >> 4, h = bsh & 15;
    const int tid = threadIdx.x;
    const int w = tid >> 6, l = tid & 63;
    const int H = l >> 5, lq = l & 31;
    const int q0 = qc * 128 + w * 32;

    const size_t hbytes = (size_t)bsh << 17;  // bsh * 65536 elems * 2B

    // staging lane constants (2 chunks of K + 2 of V per thread)
    int srowA[2], scolA[2], sdst[2];
#pragma unroll
    for (int p = 0; p < 2; p++) {
        const int c = w + p * 4;                 // chunk 0..7
        const int o = c * 1024 + l * 16;         // byte offset in tile
        srowA[p] = o >> 7;                       // key (K) / d (V^T)
        scolA[p] = (o & 127) ^ ((l >> 3) << 4);  // pre-swizzled src byte
        sdst[p]  = c * 1024;
    }

    // Q B-fragments (col=lq, k=H*8+e within each 16-k step), kept in regs.
    // Q is pre-scaled by 0.125*log2e at the QKV epilogue.
    short8 qf[4];
    {
        const char* qsrc = (const char*)Qb + hbytes + (size_t)(q0 + lq) * 128;
#pragma unroll
        for (int ks = 0; ks < 4; ks++)
            qf[ks] = *reinterpret_cast<const short8*>(qsrc + ks * 32 + H * 16);
    }

    f32x16 o0, o1;
#pragma unroll
    for (int r = 0; r < 16; r++) { o0[r] = 0.f; o1[r] = 0.f; }
    float lsum = 0.f;

    // ---- prologue: stage tile 0 into buf 0 ----
#pragma unroll
    for (int p = 0; p < 2; p++) {
        gld16((const char*)Kb + hbytes + (size_t)(srowA[p]) * 128 + scolA[p],
              Ks[0] + sdst[p]);
        gld16((const char*)Vt + hbytes + (size_t)srowA[p] * 2048 + scolA[p],
              Vs[0] + sdst[p]);
    }
    __syncthreads();

    for (int t = 0; t < 16; t++) {
        const int cur = t & 1;

        // ---- stage tile t+1 into the other buffer (hidden under compute)
        if (t + 1 < 16) {
            const int nb = cur ^ 1;
#pragma unroll
            for (int p = 0; p < 2; p++) {
                gld16((const char*)Kb + hbytes
                          + (size_t)((t + 1) * 64 + srowA[p]) * 128 + scolA[p],
                      Ks[nb] + sdst[p]);
                gld16((const char*)Vt + hbytes
                          + (size_t)srowA[p] * 2048 + (t + 1) * 128 + scolA[p],
                      Vs[nb] + sdst[p]);
            }
        }

        // ---- S^T = mfma(K, Q): rows=keys, col=q (=lq); exp2-domain scores
        f32x16 s0, s1;
#pragma unroll
        for (int r = 0; r < 16; r++) { s0[r] = 0.f; s1[r] = 0.f; }
#pragma unroll
        for (int ks = 0; ks < 4; ks++) {
            const int b0 = (lq * 128 + ks * 32 + H * 16) ^ ((lq & 7) << 4);
            short8 k0 = *reinterpret_cast<const short8*>(Ks[cur] + b0);
            short8 k1 = *reinterpret_cast<const short8*>(Ks[cur] + b0 + 4096);
            s0 = __builtin_amdgcn_mfma_f32_32x32x16_bf16(k0, qf[ks], s0, 0, 0, 0);
            s1 = __builtin_amdgcn_mfma_f32_32x32x16_bf16(k1, qf[ks], s1, 0, 0, 0);
        }

        // ---- static-max softmax: p = exp2(s) directly ----
        float pv[32];
        float ps = 0.f;
#pragma unroll
        for (int r = 0; r < 16; r++) {
            pv[r]      = __builtin_amdgcn_exp2f(s0[r]);
            pv[16 + r] = __builtin_amdgcn_exp2f(s1[r]);
        }
#pragma unroll
        for (int r = 0; r < 32; r++) ps += pv[r];
        lsum += ps;

        // ---- P redistribution via permlane32_swap + PV MFMAs ----
#pragma unroll
        for (int kf = 0; kf < 2; kf++) {
            unsigned c8[8];
#pragma unroll
            for (int i = 0; i < 8; i++)
                c8[i] = cvt_pk_bf16(pv[kf * 16 + 2 * i], pv[kf * 16 + 2 * i + 1]);
#pragma unroll
            for (int tt = 0; tt < 2; tt++) {
                const int b = tt * 4;
                unsigned u0 = c8[b + 0], u2 = c8[b + 2];
                unsigned u1 = c8[b + 1], u3 = c8[b + 3];
                permlane32_swap(u0, u2);
                permlane32_swap(u1, u3);
                union { unsigned u[4]; short8 v; } pa;
                pa.u[0] = u0; pa.u[1] = u1; pa.u[2] = u2; pa.u[3] = u3;
                const int vb0 = (lq * 128 + kf * 64 + tt * 32 + H * 16) ^ ((lq & 7) << 4);
                short8 v0 = *reinterpret_cast<const short8*>(Vs[cur] + vb0);
                short8 v1 = *reinterpret_cast<const short8*>(Vs[cur] + vb0 + 4096);
                o0 = __builtin_amdgcn_mfma_f32_32x32x16_bf16(pa.v, v0, o0, 0, 0, 0);
                o1 = __builtin_amdgcn_mfma_f32_32x32x16_bf16(pa.v, v1, o1, 0, 0, 0);
            }
        }

        // one sync per tile: drains the t+1 staging (issued a full compute
        // phase ago -> hidden) and protects buffer reuse
        if (t + 1 < 16) __syncthreads();
    }

    // ---- epilogue: normalize, pack, store (ctx bf16 hi-only) ----
    const float lt = lsum + __shfl_xor(lsum, 32);
#pragma unroll
    for (int r = 0; r < 16; r++) {
        const int qrow = (r & 3) + 8 * (r >> 2) + 4 * H;
        const float inv = 1.f / __shfl(lt, qrow);
        const size_t tok = (size_t)bseg * 1024 + q0 + qrow;
        unsigned short* p0 = ctx + tok * 1024 + h * 64 + lq;
        const unsigned pk = cvt_pk_bf16(o0[r] * inv, o1[r] * inv);
        p0[0]  = (unsigned short)pk;
        p0[32] = (unsigned short)(pk >> 16);
    }
}

// ---------------------------------------------------------------------------
extern "C" void kernel_launch(void* const* d_in, const int* in_sizes, int n_in,
                              void* d_out, int out_size, void* d_ws, size_t ws_size,
                              hipStream_t stream)
{
    const float* x    = (const float*)d_in[0];
    const float* Wqkv = (const float*)d_in[1];
    const float* bqkv = (const float*)d_in[2];
    const float* Wout = (const float*)d_in[3];
    const float* bout = (const float*)d_in[4];
    float* out = (float*)d_out;

    // workspace layout
    char* ws = (char*)d_ws;
    unsigned short* Ax  = (unsigned short*)(ws);                    // 16 MB (hi only)
    unsigned short* Wqt = (unsigned short*)(ws + 33554432);         //  6 MB (hi only)
    unsigned short* Wot = (unsigned short*)(ws + 46137344);         //  2 MB (hi only)
    unsigned short* Qb  = (unsigned short*)(ws + 50331648);         // 16 MB
    unsigned short* Kb  = (unsigned short*)(ws + 67108864);         // 16 MB
    unsigned short* Vt  = (unsigned short*)(ws + 100663296);        // 16 MB
    unsigned short* ctx = (unsigned short*)(ws + 117440512);        // 16 MB (hi only)

    // all input prep in one launch: 8192 gather blocks + 4096 transpose blocks
    prep_all_kernel<<<8192 + 4096, 256, 0, stream>>>(x, Wqkv, Wout, Ax, Wqt, Wot);

    // QKV projection (pure bf16, K=1024, 16 tiles) -> Q(scaled)/K + Vt.
    // grid = (8192/128)*(3072/256) = 64*12 = 768 blocks = 3 exact rounds.
    gemm2p_kernel<1, 0><<<768, 512, 0, stream>>>(
        Ax, Wqt, bqkv, (float*)nullptr, Qb, Kb, Vt, 3072, 12);

    // attention: 1024 blocks (4/CU), q32/wave
    attn_mfma_kernel<<<1024, 256, 0, stream>>>(Qb, Kb, Vt, ctx);

    // output projection (pure bf16 ctx, 16 tiles) -> fp32 out.
    // grid = 64*4 = 256 blocks = 1 round.
    gemm2p_kernel<0, 0><<<256, 512, 0, stream>>>(
        ctx, Wot, bout, out, (unsigned short*)nullptr,
        (unsigned short*)nullptr, (unsigned short*)nullptr, 1024, 4);
}